// Round 6
// baseline (120.176 us; speedup 1.0000x reference)
//
#include <hip/hip_runtime.h>

// out[b,n] = prod_d psi((x[b,d]-c[n,d])/s[n,d]),  psi(z)=(1-z^2)exp(-z^2/2)
// Per 16-d group: prod psi = [prod(1-wr)] * exp2(-0.72135*sum wr), wr=(x-c)^2/s^2.
// Group bound: |1-wr| <= ~99 -> p <= 99^16 ~ 8.5e31 < 3.4e38; group factor <= 1.
// fp32-only (f16 would put ~1e-3 rel error into the exponent).
//
// R14: orthogonal decomposition. lane=n eliminated suspects one by one
// (R7==R8 occupancy, R11 scalar-x, R13 clean vmcnt pipeline) yet every
// non-spilling variant sits at 85-89us (wavelet ~41 vs 13.7us slot floor).
// The invariant is the decomposition: per-(bi,h) broadcast ds_read_b128
// (4096/CU x ~12cy ~ 20us LDS-unit occupancy) + pk extract/epilogue bloat.
// Flip to lane=b:
//  - x[64 d] register-resident per lane (one-time LDS transpose, padded
//    stride 65 -> 2-way=free bank access); NO steady-state LDS/VMEM reads
//  - params wave-uniform -> s_load_dwordx16 on the SMEM pipe (like R8's x);
//    5-op chain satisfies the 1-SGPR-per-VALU-inst rule:
//    t=x-c(S); w=t*t; wr=w*rr(S); p=fma(-wr,p,p); s2+=wr
//  - floor 268M*5/78.6T ~ 17us + ~8% merge ~ 18.5us
//  - grid 128 b-strips x 8 n-groups = 1024 blocks, 4 waves x 16 n,
//    LDS 33KB/block -> exactly 4 blocks/CU, single round, no tail
//  - out staged in padded LDS, cooperative coalesced flush
// VGPR: xr 64 + temps ~25 = ~90-110 < 128 cap (launch_bounds(256,2)).

#define DD 64

__global__ __launch_bounds__(256)
void prep(const float* __restrict__ c, const float* __restrict__ s,
          float2* __restrict__ pq, int total) {
    int i = blockIdx.x * 256 + threadIdx.x;   // over N*DD, layout [n][d]
    if (i < total) {
        float sv = s[i];
        pq[i] = make_float2(c[i], 1.0f / (sv * sv));   // {c, 1/s^2}
    }
}

__global__ __launch_bounds__(256, 2)
void wavelet_kernel(const float* __restrict__ x,
                    const float2* __restrict__ pq,
                    float* __restrict__ out, int B, int N) {
    __shared__ float xs[64 * 65];   // x transpose stage, padded rows (16.6 KB)
    __shared__ float ol[64 * 65];   // out stage, padded rows (16.6 KB)

    int t = threadIdx.x;
    int lane = t & 63;
    int wv = __builtin_amdgcn_readfirstlane(t >> 6);   // wave-uniform
    int bblk = blockIdx.x * 64;                        // block's 64 b rows
    int nblk = blockIdx.y * 64;                        // block's 64 n cols

    // stage x[bblk..+63][0..63] coalesced (1024 float4, 4/thread), pad 65
    {
        const float4* xg = (const float4*)(x + (size_t)bblk * DD);
#pragma unroll
        for (int j = 0; j < 4; ++j) {
            int idx = j * 256 + t;
            int row = idx >> 4, c4 = idx & 15;
            float4 v = xg[idx];
            float* p = &xs[row * 65 + c4 * 4];
            p[0] = v.x; p[1] = v.y; p[2] = v.z; p[3] = v.w;
        }
    }
    __syncthreads();

    // transpose into registers: lane = b owns x[b][0..63] (64 VGPRs).
    // bank = (65*lane+d)%32 = (lane+d)%32 -> 2 lanes/bank = free (m136).
    float xr[DD];
#pragma unroll
    for (int d = 0; d < DD; ++d) xr[d] = xs[lane * 65 + d];

    // n loop: wave wv handles n = nblk + wv*16 .. +15
#pragma unroll 1
    for (int ni = 0; ni < 16; ++ni) {
        int n = nblk + wv * 16 + ni;
        const float2* P = pq + (size_t)n * DD;   // wave-uniform -> s_load
        float acc = 1.0f;
#pragma unroll
        for (int k = 0; k < 4; ++k) {            // 4 chunks of 16 d
            float p = 1.0f, s2 = 0.0f;
#pragma unroll
            for (int i = 0; i < 16; ++i) {
                float2 q = P[k * 16 + i];        // {c, rr} from SGPRs
                float tt = xr[k * 16 + i] - q.x; // 1 SGPR op
                float w  = tt * tt;              // VGPR only
                float wr = w * q.y;              // 1 SGPR op
                p = __builtin_fmaf(-wr, p, p);   // p *= (1-wr)
                s2 += wr;
            }
            acc *= p * __builtin_exp2f(-0.72134752f * s2);
        }
        // stage output: bank = (lane + wv*16 + ni)%32 -> 2-way = free
        ol[lane * 65 + wv * 16 + ni] = acc;
    }
    __syncthreads();

    // cooperative coalesced flush: 64 rows x 64 cols, 16 floats/thread
    {
        int row = t >> 2, seg = t & 3;
        float* orow = out + (size_t)(bblk + row) * N + nblk + seg * 16;
        const float* l = &ol[row * 65 + seg * 16];
#pragma unroll
        for (int j4 = 0; j4 < 4; ++j4) {
            float4 v = make_float4(l[j4 * 4], l[j4 * 4 + 1],
                                   l[j4 * 4 + 2], l[j4 * 4 + 3]);
            ((float4*)orow)[j4] = v;   // consecutive t -> consecutive 16 B
        }
    }
}

extern "C" void kernel_launch(void* const* d_in, const int* in_sizes, int n_in,
                              void* d_out, int out_size, void* d_ws, size_t ws_size,
                              hipStream_t stream) {
    const float* x = (const float*)d_in[0];
    const float* c = (const float*)d_in[1];
    const float* s = (const float*)d_in[2];
    float* out = (float*)d_out;

    int B = in_sizes[0] / DD;    // 8192
    int N = in_sizes[1] / DD;    // 512

    float2* pq = (float2*)d_ws;  // N*DD*8 B = 256 KB

    int total = N * DD;
    prep<<<(total + 255) / 256, 256, 0, stream>>>(c, s, pq, total);

    // grid: x = b strips of 64 (lane=b), y = n groups of 64 (4 waves x 16)
    dim3 grid(B / 64, N / 64);   // 128 x 8 = 1024 blocks = 4 blocks/CU
    wavelet_kernel<<<grid, 256, 0, stream>>>(x, pq, out, B, N);
}

// Round 7
// 98.309 us; speedup vs baseline: 1.2224x; 1.2224x over previous
//
#include <hip/hip_runtime.h>

// out[b,n] = prod_d psi((x[b,d]-c[n,d])/s[n,d]),  psi(z)=(1-z^2)exp(-z^2/2)
// Per 16-d group: prod psi = [prod(1-z^2)] * exp2(-0.72135*sum z^2), z via
// z = fma(x, r, -cr) with prep-computed {cr, r}. Group bound: |1-z^2|<=~1e2
// -> p <= 1e32 < 3.4e38; each group factor <= 1 -> acc in [0,1]. fp32-only.
//
// R15: lane=b kept (R14 finally gave clean counters: FETCH 3.4MB / WRITE
// 17.2MB logical, no spill; VALUBusy 33% at 62.6us -> VALU-busy time
// ~20.7us == the issue model; wave stalled 2/3 of time). Stall localized:
// wave-uniform params went to the SMEM path (s_load_dwordx16, 512B/ni,
// chunked under the 112-SGPR budget -> serialized lgkmcnt waits inside
// every ni; unroll-1 blocks cross-ni prefetch; 2048 K$-thrashing scalar
// loads/CU). Fix: params OFF SMEM -- stage the block's whole param slab
// (64n x 64d x 8B = 32KB) into LDS once, coalesced, in the prologue.
// Inner loop: ZERO VMEM/SMEM; only uniform-address ds_read_b128 broadcasts
// (conflict-free, compiler emits counted lgkmcnt) + register-resident x.
// LDS pool phase-aliased (x-transpose buffer dies before params overwrite
// it): 32KB params + 17.4KB out-stage = 49.4KB -> 3 blocks/CU.
// VGPR: xr 64 + temps ~25 = ~90 < 128 cap (launch_bounds(256,2)).

#define DD 64

typedef float v4f __attribute__((ext_vector_type(4)));

__global__ __launch_bounds__(256)
void prep(const float* __restrict__ c, const float* __restrict__ s,
          float2* __restrict__ pq, int total) {
    int i = blockIdx.x * 256 + threadIdx.x;   // over N*DD, layout [n][d]
    if (i < total) {
        float r = 1.0f / s[i];
        pq[i] = make_float2(c[i] * r, r);     // {c/s, 1/s}
    }
}

__global__ __launch_bounds__(256, 2)
void wavelet_kernel(const float* __restrict__ x,
                    const float2* __restrict__ pq,
                    float* __restrict__ out, int B, int N) {
    // pool: phase1 xs[64][65] f32 (16.64KB) ; phase2 par[64n][64d] float2
    // (32KB, overlaps xs) + ol[4][64][17] f32 (17.4KB). total 50.5KB.
    __shared__ __align__(16) char pool[32 * 1024 + 4 * 64 * 17 * 4];
    float* xs = (float*)pool;                       // [64][65]
    v4f*   par = (v4f*)pool;                        // [64n][32 qwords]
    float* ol = (float*)(pool + 32 * 1024);         // [wv][64][17]

    int t = threadIdx.x;
    int lane = t & 63;
    int wv = __builtin_amdgcn_readfirstlane(t >> 6);   // wave-uniform
    int bblk = blockIdx.x * 64;                        // block's 64 b rows
    int nblk = blockIdx.y * 64;                        // block's 64 n cols

    // phase 1: stage x[bblk..+63][0..63] coalesced (1024 qw, 4/thread), pad 65
    {
        const float4* xg = (const float4*)(x + (size_t)bblk * DD);
#pragma unroll
        for (int j = 0; j < 4; ++j) {
            int idx = j * 256 + t;
            int row = idx >> 4, c4 = idx & 15;
            float4 v = xg[idx];
            float* p = &xs[row * 65 + c4 * 4];
            p[0] = v.x; p[1] = v.y; p[2] = v.z; p[3] = v.w;
        }
    }
    __syncthreads();

    // transpose into registers: lane = b owns x[b][0..63] (64 VGPRs).
    // bank = (65*lane+d)%32 = (lane+d)%32 -> 2 lanes/bank = free (m136).
    float xr[DD];
#pragma unroll
    for (int d = 0; d < DD; ++d) xr[d] = xs[lane * 65 + d];
    __syncthreads();   // xs dead -> par may overwrite the region

    // phase 2: stage param slab pq[nblk..+63][*] = 32KB, coalesced,
    // 2048 qwords, 8 per thread (dwordx4 + ds_write_b128)
    {
        const v4f* pg = (const v4f*)(pq + (size_t)nblk * DD);
#pragma unroll
        for (int j = 0; j < 8; ++j) par[j * 256 + t] = pg[j * 256 + t];
    }
    __syncthreads();

    // n loop: wave wv handles n = nblk + wv*16 .. +15.
    // inner loop: no VMEM, no SMEM -- only uniform ds_read broadcasts.
    const v4f* Pw = par + (size_t)(wv * 16) * 32;   // 32 qw per n
#pragma unroll 1
    for (int ni = 0; ni < 16; ++ni) {
        const v4f* Pn = Pw + ni * 32;
        float acc = 1.0f;
#pragma unroll
        for (int k = 0; k < 4; ++k) {            // 4 chunks of 16 d
            float p = 1.0f, s2 = 0.0f;
#pragma unroll
            for (int i = 0; i < 8; ++i) {        // 2 d per qword
                v4f q = Pn[k * 8 + i];           // {cr0, r0, cr1, r1} bcast
                float z0 = __builtin_fmaf(xr[k * 16 + 2 * i], q.y, -q.x);
                float z1 = __builtin_fmaf(xr[k * 16 + 2 * i + 1], q.w, -q.z);
                float w0 = z0 * z0;
                float w1 = z1 * z1;
                p = __builtin_fmaf(-w0, p, p);   // p *= (1-w0)
                p = __builtin_fmaf(-w1, p, p);
                s2 += w0;
                s2 += w1;
            }
            acc *= p * __builtin_exp2f(-0.72134752f * s2);
        }
        // out stage: bank = (lane*17 + ni)%32, 17 odd -> 2-way = free
        ol[(wv * 64 + lane) * 17 + ni] = acc;
    }

    // flush: per-wave own slab (no barrier needed; same-wave ds ordering
    // via lgkmcnt). lane l -> row b=l>>2, cols (l&3)*4..+3: one dwordx4
    // per lane per g covers 16 rows x 64B contiguous segments.
#pragma unroll
    for (int g = 0; g < 4; ++g) {
        int row = (lane >> 2) + 16 * g;
        int col = (lane & 3) * 4;
        const float* l = &ol[(wv * 64 + row) * 17 + col];
        float4 v = make_float4(l[0], l[1], l[2], l[3]);
        float* orow = out + (size_t)(bblk + row) * N + nblk + wv * 16 + col;
        *(float4*)orow = v;
    }
}

extern "C" void kernel_launch(void* const* d_in, const int* in_sizes, int n_in,
                              void* d_out, int out_size, void* d_ws, size_t ws_size,
                              hipStream_t stream) {
    const float* x = (const float*)d_in[0];
    const float* c = (const float*)d_in[1];
    const float* s = (const float*)d_in[2];
    float* out = (float*)d_out;

    int B = in_sizes[0] / DD;    // 8192
    int N = in_sizes[1] / DD;    // 512

    float2* pq = (float2*)d_ws;  // N*DD*8 B = 256 KB

    int total = N * DD;
    prep<<<(total + 255) / 256, 256, 0, stream>>>(c, s, pq, total);

    // grid: x = b strips of 64 (lane=b), y = n groups of 64 (4 waves x 16)
    dim3 grid(B / 64, N / 64);   // 128 x 8 = 1024 blocks
    wavelet_kernel<<<grid, 256, 0, stream>>>(x, pq, out, B, N);
}